// Round 1
// baseline (23.584 us; speedup 1.0000x reference)
//
#include <hip/hip_runtime.h>
#include <hip/hip_bf16.h>
#include <cstdint>

#define N 2048
#define BS 16
#define F_OUT 40
#define MAXDEG 256
#define LOG2E 1.44269504088896340736f

// ws layout:
//   byte 0    : float scal[32]   -> [0]=s1*log2e, [1]=s2*log2e, [2..17]=xmean[b]
//   byte 128  : int counts[N]    -> 8 KB
//   byte 8320 : ushort lists[N*MAXDEG] -> 1 MB
// total ~1.06 MB

// ---------------- kernel C: scalars (s1, s2, per-batch mean of x) -----------
__global__ __launch_bounds__(256) void k_scal(const float* __restrict__ x,
                                              const float* __restrict__ W,
                                              const float* __restrict__ a,
                                              float* __restrict__ scal) {
    __shared__ float sd[256];
    const int t = threadIdx.x;
    float p1 = 0.f, p2 = 0.f;
    if (t < F_OUT) {
        float w = W[t];
        p1 = w * a[t];
        p2 = w * a[F_OUT + t];
    }
    sd[t] = p1; __syncthreads();
    for (int off = 128; off; off >>= 1) {
        if (t < off) sd[t] += sd[t + off];
        __syncthreads();
    }
    if (t == 0) scal[0] = sd[0] * LOG2E;
    __syncthreads();
    sd[t] = p2; __syncthreads();
    for (int off = 128; off; off >>= 1) {
        if (t < off) sd[t] += sd[t + off];
        __syncthreads();
    }
    if (t == 0) scal[1] = sd[0] * LOG2E;
    __syncthreads();
    // per-batch mean of x: 16 batches x 16 threads each
    const int b = t >> 4, l = t & 15;
    float s = 0.f;
    for (int k = 0; k < N / 16; ++k) s += x[b * N + l + (k << 4)];
    sd[t] = s; __syncthreads();
    if (t < BS) {
        float tot = 0.f;
        for (int u = 0; u < 16; ++u) tot += sd[t * 16 + u];
        scal[2 + t] = tot * (1.0f / N);
    }
}

// ---------------- kernel A: CSR build (one block per row) -------------------
__global__ __launch_bounds__(256) void k_build(const float* __restrict__ adj,
                                               int* __restrict__ counts,
                                               unsigned short* __restrict__ lists) {
    const int i = blockIdx.x;
    const int t = threadIdx.x;
    const int wv = t >> 6, lane = t & 63;
    __shared__ int wcnt[4];
    unsigned long long m[2][4];

    const float4* arow = reinterpret_cast<const float4*>(adj + (size_t)i * N);
    int cnt = 0;
    #pragma unroll
    for (int it = 0; it < 2; ++it) {
        float4 v = arow[wv * 128 + it * 64 + lane];
        m[it][0] = __ballot(v.x > 0.f);
        m[it][1] = __ballot(v.y > 0.f);
        m[it][2] = __ballot(v.z > 0.f);
        m[it][3] = __ballot(v.w > 0.f);
        cnt += __popcll(m[it][0]) + __popcll(m[it][1]) +
               __popcll(m[it][2]) + __popcll(m[it][3]);
    }
    if (lane == 0) wcnt[wv] = cnt;
    __syncthreads();
    int base = 0;
    for (int u = 0; u < wv; ++u) base += wcnt[u];
    const unsigned long long lt = (1ull << lane) - 1ull;
    #pragma unroll
    for (int it = 0; it < 2; ++it) {
        const int f4idx = wv * 128 + it * 64 + lane;
        #pragma unroll
        for (int k = 0; k < 4; ++k) {
            const unsigned long long mask = m[it][k];
            if ((mask >> lane) & 1ull) {
                int pos = base + __popcll(mask & lt);
                if (pos < MAXDEG)
                    lists[i * MAXDEG + pos] = (unsigned short)(f4idx * 4 + k);
            }
            base += __popcll(mask);
        }
    }
    if (t == 0) {
        int tot = wcnt[0] + wcnt[1] + wcnt[2] + wcnt[3];
        counts[i] = tot < MAXDEG ? tot : MAXDEG;
    }
}

// ---------------- kernel B: main (one wave per (b,i)) -----------------------
__global__ __launch_bounds__(256) void k_main(const float* __restrict__ x,
                                              const int* __restrict__ counts,
                                              const unsigned short* __restrict__ lists,
                                              const float* __restrict__ scal,
                                              const float* __restrict__ W,
                                              float* __restrict__ out) {
    const int wv = threadIdx.x >> 6, lane = threadIdx.x & 63;
    const int gid = blockIdx.x * 4 + wv;        // gid = b*N + i
    const int b = gid >> 11, i = gid & (N - 1);

    const float s1L = scal[0], s2L = scal[1];
    const float xi = x[b * N + i];
    const float zi2 = s1L * xi;
    const int cnt = counts[i];

    float d = 0.f, w = 0.f;
    for (int t = lane; t < cnt; t += 64) {
        const int jn = lists[i * MAXDEG + t];
        const float xj = x[b * N + jn];
        const float z2 = fmaf(s2L, xj, zi2);   // z * log2(e); sign(z2)==sign(z)
        float e = exp2f(z2);
        e = (z2 > 0.f) ? e : 0.f;
        d += e;
        w = fmaf(e, xj, w);
    }
    #pragma unroll
    for (int off = 32; off; off >>= 1) {
        d += __shfl_xor(d, off);
        w += __shfl_xor(w, off);
    }
    const float p = (d > 0.f) ? (w / d) : scal[2 + b];

    if (lane < F_OUT) {
        const float v = p * W[lane];
        const float o = (v > 0.f) ? v : expm1f(v);
        out[(size_t)gid * F_OUT + lane] = o;
    }
}

extern "C" void kernel_launch(void* const* d_in, const int* in_sizes, int n_in,
                              void* d_out, int out_size, void* d_ws, size_t ws_size,
                              hipStream_t stream) {
    const float* x   = (const float*)d_in[0];
    const float* adj = (const float*)d_in[1];
    // d_in[2] (ext_input) and d_in[3] (side_input) are unused by the reference
    const float* W   = (const float*)d_in[4];
    const float* a   = (const float*)d_in[5];
    float* out = (float*)d_out;

    char* ws = (char*)d_ws;
    float* scal = (float*)ws;
    int* counts = (int*)(ws + 128);
    unsigned short* lists = (unsigned short*)(ws + 128 + sizeof(int) * N);

    k_scal<<<1, 256, 0, stream>>>(x, W, a, scal);
    k_build<<<N, 256, 0, stream>>>(adj, counts, lists);
    k_main<<<BS * N / 4, 256, 0, stream>>>(x, counts, lists, scal, W, out);
}

// Round 2
// 16.095 us; speedup vs baseline: 1.4654x; 1.4654x over previous
//
#include <hip/hip_runtime.h>
#include <hip/hip_bf16.h>
#include <cstdint>

#define N 2048
#define BS 16
#define F_OUT 40
#define MAXDEG 256
#define LOG2E 1.44269504088896340736f

// One block per adjacency row i. 256 threads = 4 waves.
//  - load adj row (8 KB) coalesced, ballot-compact neighbor indices into LDS
//  - wave 0 computes s1 = W.a1, s2 = W.a2 (40 MACs) from cached W/a
//  - wave wv handles batches {wv, wv+4, wv+8, wv+12}: scalar softmax over
//    neighbors, p = sum(e*xj)/sum(e), fallback to mean(x[b,:]) if no valid
//    logit (matches reference softmax of all-NEG row = uniform over N)
//  - epilogue: out[(b*N+i)*40 + f] = elu(p * W[f])
__global__ __launch_bounds__(256) void k_fused(const float* __restrict__ x,
                                               const float* __restrict__ adj,
                                               const float* __restrict__ W,
                                               const float* __restrict__ a,
                                               float* __restrict__ out) {
    const int i = blockIdx.x;
    const int t = threadIdx.x;
    const int wv = t >> 6, lane = t & 63;

    __shared__ unsigned short list[MAXDEG];
    __shared__ int wcnt[4];
    __shared__ int s_cnt;
    __shared__ float s_s1, s_s2;

    // ---- issue adj-row loads early (latency overlap with s1/s2 compute) ----
    const float4* arow = reinterpret_cast<const float4*>(adj + (size_t)i * N);
    float4 v0 = arow[wv * 128 + lane];        // f4 idx wv*128 + lane
    float4 v1 = arow[wv * 128 + 64 + lane];   // f4 idx wv*128 + 64 + lane

    // ---- s1, s2 (wave 0 only; independent loads overlap adj latency) ----
    if (wv == 0) {
        float p1 = 0.f, p2 = 0.f;
        if (lane < F_OUT) {
            const float w = W[lane];
            p1 = w * a[lane];
            p2 = w * a[F_OUT + lane];
        }
        #pragma unroll
        for (int off = 32; off; off >>= 1) {
            p1 += __shfl_xor(p1, off);
            p2 += __shfl_xor(p2, off);
        }
        if (lane == 0) { s_s1 = p1 * LOG2E; s_s2 = p2 * LOG2E; }
    }

    // ---- ballot compaction of adj row into LDS list ----
    unsigned long long m[2][4];
    int cnt = 0;
    m[0][0] = __ballot(v0.x > 0.f);
    m[0][1] = __ballot(v0.y > 0.f);
    m[0][2] = __ballot(v0.z > 0.f);
    m[0][3] = __ballot(v0.w > 0.f);
    m[1][0] = __ballot(v1.x > 0.f);
    m[1][1] = __ballot(v1.y > 0.f);
    m[1][2] = __ballot(v1.z > 0.f);
    m[1][3] = __ballot(v1.w > 0.f);
    #pragma unroll
    for (int it = 0; it < 2; ++it)
        cnt += __popcll(m[it][0]) + __popcll(m[it][1]) +
               __popcll(m[it][2]) + __popcll(m[it][3]);
    if (lane == 0) wcnt[wv] = cnt;
    __syncthreads();

    int base = 0;
    for (int u = 0; u < wv; ++u) base += wcnt[u];
    const unsigned long long lt = (1ull << lane) - 1ull;
    #pragma unroll
    for (int it = 0; it < 2; ++it) {
        const int f4idx = wv * 128 + it * 64 + lane;
        #pragma unroll
        for (int k = 0; k < 4; ++k) {
            const unsigned long long mask = m[it][k];
            if ((mask >> lane) & 1ull) {
                const int pos = base + __popcll(mask & lt);
                if (pos < MAXDEG)
                    list[pos] = (unsigned short)(f4idx * 4 + k);
            }
            base += __popcll(mask);
        }
    }
    if (t == 0) {
        int tot = wcnt[0] + wcnt[1] + wcnt[2] + wcnt[3];
        s_cnt = tot < MAXDEG ? tot : MAXDEG;
    }
    __syncthreads();

    const int deg = s_cnt;
    const float s1 = s_s1, s2 = s_s2;
    const float wl = (lane < F_OUT) ? W[lane] : 0.f;

    #pragma unroll
    for (int bb = 0; bb < 4; ++bb) {
        const int b = wv + bb * 4;
        const float* __restrict__ xb = x + b * N;
        const float zi2 = s1 * xb[i];

        float d = 0.f, ws = 0.f;
        for (int tt = lane; tt < deg; tt += 64) {
            const int jn = list[tt];
            const float xj = xb[jn];
            const float z2 = fmaf(s2, xj, zi2);  // z*log2(e); sign preserved
            const float e = (z2 > 0.f) ? exp2f(z2) : 0.f;
            d += e;
            ws = fmaf(e, xj, ws);
        }
        #pragma unroll
        for (int off = 32; off; off >>= 1) {
            d += __shfl_xor(d, off);
            ws += __shfl_xor(ws, off);
        }

        float p;
        if (d > 0.f) {            // wave-uniform (post-reduction)
            p = ws / d;
        } else {
            // all logits invalid -> reference softmax is uniform over N
            float s = 0.f;
            for (int k = lane; k < N; k += 64) s += xb[k];
            #pragma unroll
            for (int off = 32; off; off >>= 1) s += __shfl_xor(s, off);
            p = s * (1.0f / N);
        }

        if (lane < F_OUT) {
            const float v = p * wl;
            out[((size_t)(b * N + i)) * F_OUT + lane] =
                (v > 0.f) ? v : expm1f(v);
        }
    }
}

extern "C" void kernel_launch(void* const* d_in, const int* in_sizes, int n_in,
                              void* d_out, int out_size, void* d_ws, size_t ws_size,
                              hipStream_t stream) {
    const float* x   = (const float*)d_in[0];
    const float* adj = (const float*)d_in[1];
    // d_in[2] (ext_input) and d_in[3] (side_input) are unused by the reference
    const float* W   = (const float*)d_in[4];
    const float* a   = (const float*)d_in[5];
    float* out = (float*)d_out;

    k_fused<<<N, 256, 0, stream>>>(x, adj, W, a, out);
}